// Round 7
// baseline (124.173 us; speedup 1.0000x reference)
//
#include <hip/hip_runtime.h>
#include <math.h>

// Fully fused quanvolution. 36->128 3x3 conv on bf16 MFMA
// (v_mfma_f32_32x32x16_bf16) as shift-GEMMs, K-packed. Two images per
// 256-thread block, software-pipelined, 2 blocks/CU.
//
// Round-16 changes vs round-15:
//   * nt-PAIR waves: wave (np,mh) = (wv&1, wv>>1) computes TWO output
//     channel tiles (nt = 2np, 2np+1) over an mt-half (0-3 / 4-6).
//     Before: all 4 waves read the IDENTICAL actT A-fragments (nt-split
//     -> 4x A redundancy), 644 wave-LDS-reads per image-block. Now each
//     A-read feeds 2 MFMAs (one per nt) -> 336 reads (-48%) on the
//     busiest pipe. Two independent 21-MFMA chains per wave (accA/accB)
//     also double latency-hiding ILP.
//   * Classifier fold: both nt fold into the same a11[k] (output = sum
//     over all features) -> per-image register state unchanged.
//   * Register audit: bfr 168 + acc 32 + non-hoist ~40 = ~235 < 256 cap
//     ((256,2)). Spill tripwire: WRITE_SIZE / scratch in disasm.
//
// d_ws:
//   [0, 86016)        bfrag [nt][21 frags][lane][8 bf16]
//                       frags 0..17: t*2+ks (ic = ks*16+hk*8+j)
//                       frags 18..20: packed quantum (k=(tap,ch))
//   [86016, +344064)  clsTT fp32 [nt=4][mt=7][q=4][hk=2][l31=32][k12]

typedef __bf16 bf16x8 __attribute__((ext_vector_type(8)));
typedef __bf16 bf16x4 __attribute__((ext_vector_type(4)));
typedef float  f32x16 __attribute__((ext_vector_type(16)));

union Pack8 { __bf16 h[8]; uint4 v; };
union QPair { struct { bf16x4 lo, hi; } p; bf16x8 v; };

// one element per thread: 43008 bfrag elems + 86016 clsTT elems (incl. pad)
__global__ __launch_bounds__(256) void prep(
    const float* __restrict__ fus_w,  // (128,36,3,3)
    const float* __restrict__ cls_w,  // (10,6272)
    const float* __restrict__ reg_w,  // (6272)
    __bf16* __restrict__ bfrag,       // 43008 bf16
    float* __restrict__ clsTT)        // 86016 floats
{
    const int gid = blockIdx.x * 256 + threadIdx.x;
    if (gid < 43008) {
        const int j    = gid & 7;
        const int frag = gid >> 3;
        const int lane = frag & 63;
        const int rest = frag >> 6;         // 0..83
        const int m  = rest % 21;
        const int nt = rest / 21;
        const int n  = nt * 32 + (lane & 31);
        const int hk = lane >> 5;
        float v;
        if (m < 18) {
            const int t = m >> 1, ks = m & 1;
            const int ic = ks * 16 + hk * 8 + j;        // 0..31, all real
            v = fus_w[n * 324 + ic * 9 + t];
        } else {
            const int ps = m - 18;
            const int k  = hk * 8 + j;                  // 0..15
            const int tap = ps * 4 + (k >> 2);          // 0..11
            const int ch  = k & 3;
            v = (tap < 9) ? fus_w[n * 324 + (32 + ch) * 9 + tap] : 0.f;
        }
        bfrag[gid] = (__bf16)v;             // consecutive gid -> coalesced store
    } else if (gid < 43008 + 86016) {
        // clsTT element e, kk innermost -> fully coalesced writes
        const int e   = gid - 43008;
        const int kk  = e % 12;
        const int r0  = e / 12;
        const int l31 = r0 & 31;
        const int r1  = r0 >> 5;
        const int hk  = r1 & 1;
        const int r2  = r1 >> 1;
        const int q   = r2 & 3;
        const int r3  = r2 >> 2;
        const int mt  = r3 % 7;
        const int nt  = r3 / 7;
        const int oc   = nt * 32 + l31;
        const int cell = mt * 8 + q * 2 + hk;
        float v = 0.f;
        if (cell < 49 && kk < 11) {
            const int f = oc * 49 + cell;
            v = (kk < 10) ? cls_w[kk * 6272 + f] : reg_w[f];
        }
        clsTT[e] = v;
    }
}

// ---- per-patch producer: depthwise conv + pointwise + quantum -> actT,Q ----
// p = patch index 0..195 (>=196: no-op). xs has row stride 29.
__device__ __forceinline__ void patch_work(
    const int p, const float* __restrict__ xs, __bf16* __restrict__ actT,
    __bf16* __restrict__ Qt,
    const float* __restrict__ dw_w, const float* __restrict__ pw_w,
    const float* __restrict__ pw_b, const float* __restrict__ U)
{
    if (p >= 196) return;
    const int i = p / 14, j = p % 14;
    const int Y = 2 * i, X = 2 * j;

    float w9[9];
    #pragma unroll
    for (int t = 0; t < 9; ++t) w9[t] = dw_w[t];
    float dsum = 0.f;
    #pragma unroll
    for (int dy = 0; dy < 2; ++dy) {
        #pragma unroll
        for (int dx = 0; dx < 2; ++dx) {
            const int cy = Y + dy, cx = X + dx;
            #pragma unroll
            for (int ky = 0; ky < 3; ++ky) {
                const int yy = cy + ky - 1;
                if (yy < 0 || yy > 27) continue;
                #pragma unroll
                for (int kx = 0; kx < 3; ++kx) {
                    const int xx = cx + kx - 1;
                    if (xx < 0 || xx > 27) continue;
                    dsum += xs[yy * 29 + xx] * w9[ky * 3 + kx];
                }
            }
        }
    }
    const float dpool = 0.25f * dsum;

    // ds channels 0..31 -> row sp_o, chunks 0..3 of 5 (80B row stride)
    const int sp_o = (i + 1) * 16 + (j + 1);
    #pragma unroll
    for (int c8 = 0; c8 < 4; ++c8) {
        Pack8 pk;
        #pragma unroll
        for (int e = 0; e < 8; ++e)
            pk.h[e] = (__bf16)(pw_w[c8 * 8 + e] * dpool + pw_b[c8 * 8 + e]);
        ((uint4*)actT)[sp_o * 5 + c8] = pk.v;
    }

    // quantum patch
    const float p0 = xs[Y * 29 + X],       p1 = xs[Y * 29 + X + 1];
    const float p2 = xs[(Y + 1) * 29 + X], p3 = xs[(Y + 1) * 29 + X + 1];
    float c0, s0, c1, s1, c2, s2, c3, s3;
    sincosf(0.5f * p0, &s0, &c0);
    sincosf(0.5f * p1, &s1, &c1);
    sincosf(0.5f * p2, &s2, &c2);
    sincosf(0.5f * p3, &s3, &c3);
    float a01[4] = {c0 * c1, c0 * s1, s0 * c1, s0 * s1};
    float a23[4] = {c2 * c3, c2 * s3, s2 * c3, s2 * s3};
    float amp[16];
    #pragma unroll
    for (int hi = 0; hi < 4; ++hi)
        #pragma unroll
        for (int lo = 0; lo < 4; ++lo)
            amp[hi * 4 + lo] = a01[hi] * a23[lo];

    float meas[4] = {0.f, 0.f, 0.f, 0.f};
    #pragma unroll
    for (int m = 0; m < 16; ++m) {
        float st = 0.f;
        #pragma unroll
        for (int n = 0; n < 16; ++n) st = fmaf(U[m * 16 + n], amp[n], st);
        const float pm = st * st;
        meas[0] += ((m >> 3) & 1) ? -pm : pm;
        meas[1] += ((m >> 2) & 1) ? -pm : pm;
        meas[2] += ((m >> 1) & 1) ? -pm : pm;
        meas[3] += (m & 1) ? -pm : pm;
    }
    const int fbase = i * 56 + j * 4;
    #pragma unroll
    for (int w = 0; w < 4; ++w) {
        const int f  = fbase + w;
        const int ch = f / 196;               // 0..3 -> quantum chan
        const int sp = f - ch * 196;
        const int r2 = sp / 14 + 1, c2i = sp % 14 + 1;
        const int sp2 = r2 * 16 + c2i;
        Qt[sp2 * 4 + ch] = (__bf16)meas[w];
    }
}

// ---- consumer: per mt, 42 MFMAs (2 nt) off shared A-reads + fold ----
__device__ __forceinline__ void conv_fold2(
    const __bf16* __restrict__ actT, const __bf16* __restrict__ Qt,
    const bf16x8* __restrict__ bfrA, const bf16x8* __restrict__ bfrB,
    const float4* __restrict__ cls4A, const float4* __restrict__ cls4B,
    const float fbA, const float fbB, const int l31, const int hk,
    const int* __restrict__ offL, const int* __restrict__ offH,
    const int mt0, const int mt1, float* __restrict__ a11)
{
    for (int mt = mt0; mt < mt1; ++mt) {
        // lane's A-row: m' = mt*32 + l31 -> pooled cell + sub-pixel
        const int mp   = mt * 32 + l31;
        const int cell = mp >> 2;
        const int cc = (cell < 49) ? cell : 48;   // clamp garbage rows in-bounds
        const int py = (cc * 9363) >> 16;         // cc/7 for cc<56
        const int px = cc - py * 7;
        const int yy = 2 * py + ((mp >> 1) & 1);
        const int xx = 2 * px + (mp & 1);
        const int rowbase = yy * 16 + xx;

        f32x16 accA = {0.f,0.f,0.f,0.f,0.f,0.f,0.f,0.f,
                       0.f,0.f,0.f,0.f,0.f,0.f,0.f,0.f};
        f32x16 accB = {0.f,0.f,0.f,0.f,0.f,0.f,0.f,0.f,
                       0.f,0.f,0.f,0.f,0.f,0.f,0.f,0.f};

        #pragma unroll
        for (int t = 0; t < 9; ++t) {
            const int ky = t / 3, kx = t - ky * 3;
            const int row = rowbase + ky * 16 + kx;
            const __bf16* rp = actT + row * 40 + hk * 8;
            const bf16x8 af0 = *(const bf16x8*)(rp);
            const bf16x8 af1 = *(const bf16x8*)(rp + 16);
            accA = __builtin_amdgcn_mfma_f32_32x32x16_bf16(af0, bfrA[t * 2 + 0],
                                                           accA, 0, 0, 0);
            accB = __builtin_amdgcn_mfma_f32_32x32x16_bf16(af0, bfrB[t * 2 + 0],
                                                           accB, 0, 0, 0);
            accA = __builtin_amdgcn_mfma_f32_32x32x16_bf16(af1, bfrA[t * 2 + 1],
                                                           accA, 0, 0, 0);
            accB = __builtin_amdgcn_mfma_f32_32x32x16_bf16(af1, bfrB[t * 2 + 1],
                                                           accB, 0, 0, 0);
        }
        // packed quantum slices: K = (tap,ch); B rows for taps>8 are zero
        #pragma unroll
        for (int ps = 0; ps < 3; ++ps) {
            QPair u;
            u.p.lo = *(const bf16x4*)(Qt + (rowbase + offL[ps]) * 4);
            u.p.hi = *(const bf16x4*)(Qt + (rowbase + offH[ps]) * 4);
            accA = __builtin_amdgcn_mfma_f32_32x32x16_bf16(u.v, bfrA[18 + ps],
                                                           accA, 0, 0, 0);
            accB = __builtin_amdgcn_mfma_f32_32x32x16_bf16(u.v, bfrB[18 + ps],
                                                           accB, 0, 0, 0);
        }

        // epilogue: relu+pool in-lane for both nt; fold both into a11
        const float4* cwmA = cls4A + mt * 768;    // mt stride: 4*2*32*3 float4
        const float4* cwmB = cls4B + mt * 768;
        #pragma unroll
        for (int q = 0; q < 4; ++q) {
            float pvA = 0.f, pvB = 0.f;
            #pragma unroll
            for (int s = 0; s < 4; ++s) {
                const float vA = accA[q * 4 + s] + fbA;
                const float vB = accB[q * 4 + s] + fbB;
                pvA += (vA > 0.f ? vA : 0.f);
                pvB += (vB > 0.f ? vB : 0.f);
            }
            pvA *= 0.25f;
            pvB *= 0.25f;
            const float4 a0 = cwmA[q * 192 + 0];
            const float4 a1 = cwmA[q * 192 + 1];
            const float4 a2 = cwmA[q * 192 + 2];
            const float4 b0 = cwmB[q * 192 + 0];
            const float4 b1 = cwmB[q * 192 + 1];
            const float4 b2 = cwmB[q * 192 + 2];
            a11[0]  = fmaf(pvA, a0.x, fmaf(pvB, b0.x, a11[0]));
            a11[1]  = fmaf(pvA, a0.y, fmaf(pvB, b0.y, a11[1]));
            a11[2]  = fmaf(pvA, a0.z, fmaf(pvB, b0.z, a11[2]));
            a11[3]  = fmaf(pvA, a0.w, fmaf(pvB, b0.w, a11[3]));
            a11[4]  = fmaf(pvA, a1.x, fmaf(pvB, b1.x, a11[4]));
            a11[5]  = fmaf(pvA, a1.y, fmaf(pvB, b1.y, a11[5]));
            a11[6]  = fmaf(pvA, a1.z, fmaf(pvB, b1.z, a11[6]));
            a11[7]  = fmaf(pvA, a1.w, fmaf(pvB, b1.w, a11[7]));
            a11[8]  = fmaf(pvA, a2.x, fmaf(pvB, b2.x, a11[8]));
            a11[9]  = fmaf(pvA, a2.y, fmaf(pvB, b2.y, a11[9]));
            a11[10] = fmaf(pvA, a2.z, fmaf(pvB, b2.z, a11[10]));
        }
    }
}

__global__ __launch_bounds__(256, 2) void quanv_fused(
    const float* __restrict__ x,      // (B,1,28,28)
    const float* __restrict__ dw_w,   // 9
    const float* __restrict__ pw_w,   // 32
    const float* __restrict__ pw_b,   // 32
    const float* __restrict__ U,      // 16x16
    const __bf16* __restrict__ bfrag, // B fragments
    const float* __restrict__ fus_b,  // 128
    const float* __restrict__ clsTT,  // lane-ordered classifier weights
    const float* __restrict__ cls_b,  // 10
    const float* __restrict__ reg_b,  // 1
    float* __restrict__ out,          // B*10 logits, then B aux
    int B)
{
    __shared__ __align__(16) __bf16 actT[2][256 * 40];  // 40,960 B, 80 B rows
    __shared__ __align__(16) __bf16 Qt[2][256 * 4];     //  4,096 B
    __shared__ float xs[2][812];                        //  6,496 B (stride 29)
    __shared__ float red[2][48];                        //    384 B

    const int b0  = blockIdx.x * 2;
    const int b1  = b0 + 1;
    const bool two = (b1 < B);
    const int tid = threadIdx.x;

    // ---- phase 0: zero actT+Qt (halo stays zero), stage images ----
    {
        uint4 z; z.x = 0; z.y = 0; z.z = 0; z.w = 0;
        uint4* a4 = (uint4*)&actT[0][0];
        for (int i = tid; i < 2560; i += 256) a4[i] = z;
        uint4* q4 = (uint4*)&Qt[0][0];
        if (tid < 256) q4[tid] = z;
        const float* xb = x + (size_t)b0 * 784;
        const int tot = two ? 1568 : 784;
        for (int i = tid; i < tot; i += 256) {
            const int img = i / 784, r = i - img * 784;
            xs[img][r + r / 28] = xb[i];    // row stride 29
        }
    }

    const int lane = tid & 63, wv = tid >> 6;
    const int np   = wv & 1;          // nt pair: nt = 2np, 2np+1
    const int mh   = wv >> 1;         // mt half: 0 -> 0..3, 1 -> 4..6
    const int mt0  = mh ? 4 : 0, mt1 = mh ? 7 : 4;
    const int ntA  = np * 2, ntB = np * 2 + 1;
    const int l31  = lane & 31, hk = lane >> 5;
    const float fbA = fus_b[ntA * 32 + l31];
    const float fbB = fus_b[ntB * 32 + l31];
    // wave-balanced patch assignment: 49 patches per wave
    const int pidx = (lane < 49) ? wv * 49 + lane : 999;

    bf16x8 bfrA[21], bfrB[21];
    {
        const bf16x8* __restrict__ bpA = ((const bf16x8*)bfrag) + (ntA * 21 * 64 + lane);
        const bf16x8* __restrict__ bpB = ((const bf16x8*)bfrag) + (ntB * 21 * 64 + lane);
        #pragma unroll
        for (int m = 0; m < 21; ++m) { bfrA[m] = bpA[m * 64]; bfrB[m] = bpB[m * 64]; }
    }

    // per-lane-half tap offsets for the packed quantum slices
    int offL[3], offH[3];
    #pragma unroll
    for (int ps = 0; ps < 3; ++ps) {
        int tL = ps * 4 + hk * 2;
        int tH = tL + 1;
        if (tL > 8) tL = 0;       // zero-B tail: A value is a don't-care
        if (tH > 8) tH = 0;
        offL[ps] = (tL / 3) * 16 + (tL % 3);
        offH[ps] = (tH / 3) * 16 + (tH % 3);
    }

    // classifier weights, float4 view: ((...)*32 + l31)*3 float4s
    const float4* __restrict__ cls4A =
        ((const float4*)clsTT) + ((((ntA * 7) * 4) * 2 + hk) * 32 + l31) * 3;
    const float4* __restrict__ cls4B =
        ((const float4*)clsTT) + ((((ntB * 7) * 4) * 2 + hk) * 32 + l31) * 3;

    __syncthreads();

    // ---- pipeline fill: P12(img0) ----
    patch_work(pidx, &xs[0][0], &actT[0][0], &Qt[0][0], dw_w, pw_w, pw_b, U);
    __syncthreads();

    // ---- merged steady phase: P12(img1) overlaps conv(img0), no barrier ----
    float a11_0[11];
    #pragma unroll
    for (int k = 0; k < 11; ++k) a11_0[k] = 0.f;
    if (two) patch_work(pidx, &xs[1][0], &actT[1][0], &Qt[1][0], dw_w, pw_w, pw_b, U);
    conv_fold2(&actT[0][0], &Qt[0][0], bfrA, bfrB, cls4A, cls4B, fbA, fbB,
               l31, hk, offL, offH, mt0, mt1, a11_0);
    __syncthreads();

    // ---- pipeline drain: conv(img1) ----
    float a11_1[11];
    #pragma unroll
    for (int k = 0; k < 11; ++k) a11_1[k] = 0.f;
    if (two)
        conv_fold2(&actT[1][0], &Qt[1][0], bfrA, bfrB, cls4A, cls4B, fbA, fbB,
                   l31, hk, offL, offH, mt0, mt1, a11_1);

    // ---- reduce + output both images ----
    #pragma unroll
    for (int k = 0; k < 11; ++k) {
        float a = a11_0[k];
        float c = a11_1[k];
        #pragma unroll
        for (int off = 32; off > 0; off >>= 1) {
            a += __shfl_down(a, off, 64);
            c += __shfl_down(c, off, 64);
        }
        if (lane == 0) { red[0][k * 4 + wv] = a; red[1][k * 4 + wv] = c; }
    }
    __syncthreads();
    if (tid < 11) {
        const float v = red[0][tid * 4] + red[0][tid * 4 + 1]
                      + red[0][tid * 4 + 2] + red[0][tid * 4 + 3];
        if (tid < 10) out[b0 * 10 + tid] = v + cls_b[tid];
        else          out[B * 10 + b0]   = v + reg_b[0];
    } else if (two && tid >= 64 && tid < 75) {
        const int k = tid - 64;
        const float v = red[1][k * 4] + red[1][k * 4 + 1]
                      + red[1][k * 4 + 2] + red[1][k * 4 + 3];
        if (k < 10) out[b1 * 10 + k] = v + cls_b[k];
        else        out[B * 10 + b1] = v + reg_b[0];
    }
}

extern "C" void kernel_launch(void* const* d_in, const int* in_sizes, int n_in,
                              void* d_out, int out_size, void* d_ws, size_t ws_size,
                              hipStream_t stream) {
    const float* x    = (const float*)d_in[0];
    const float* dw_w = (const float*)d_in[1];
    const float* pw_w = (const float*)d_in[2];
    const float* pw_b = (const float*)d_in[3];
    const float* U    = (const float*)d_in[4];
    const float* fw   = (const float*)d_in[5];
    const float* fb   = (const float*)d_in[6];
    const float* cw   = (const float*)d_in[7];
    const float* cb   = (const float*)d_in[8];
    const float* rw   = (const float*)d_in[9];
    const float* rb   = (const float*)d_in[10];
    const int B = in_sizes[0] / 784;

    __bf16* bfrag = (__bf16*)d_ws;                   // 86,016 B
    float*  clsTT = (float*)((char*)d_ws + 86016);   // 344,064 B

    prep<<<(43008 + 86016 + 255) / 256, 256, 0, stream>>>(fw, cw, rw, bfrag, clsTT);
    const int nblk = (B + 1) / 2;
    quanv_fused<<<nblk, 256, 0, stream>>>(x, dw_w, pw_w, pw_b, U, bfrag, fb,
                                          clsTT, cb, rb, (float*)d_out, B);
}

// Round 8
// 110.749 us; speedup vs baseline: 1.1212x; 1.1212x over previous
//
#include <hip/hip_runtime.h>
#include <math.h>

// Fully fused quanvolution. 36->128 3x3 conv on bf16 MFMA
// (v_mfma_f32_32x32x16_bf16) as shift-GEMMs, K-packed. Two images per
// 256-thread block, software-pipelined, 2 blocks/CU (round-15 structure).
//
// Round-17 changes vs round-15 (round-16 nt-pair REVERTED: allocator
// pins ~128 VGPR and spilled the doubled bfr hoist -> 11.9MB scratch
// writes, 38->57us; register-based A-sharing is permanently off):
//   * Dual accumulator in conv_fold, tested IN ISOLATION (r12 bundled it
//     with two regressions): ks=0 taps -> acc0, ks=1 taps -> acc1,
//     quantum slices split 2/1. The 21-MFMA serial chain (~420 cyc/mt,
//     unhidable at 2 waves/SIMD) becomes two ~10-chains. +16 VGPR only
//     (124 -> ~140); no LDS, phase, or read-count change.
//
// d_ws:
//   [0, 86016)        bfrag [nt][21 frags][lane][8 bf16]
//                       frags 0..17: t*2+ks (ic = ks*16+hk*8+j)
//                       frags 18..20: packed quantum (k=(tap,ch))
//   [86016, +344064)  clsTT fp32 [nt=4][mt=7][q=4][hk=2][l31=32][k12]

typedef __bf16 bf16x8 __attribute__((ext_vector_type(8)));
typedef __bf16 bf16x4 __attribute__((ext_vector_type(4)));
typedef float  f32x16 __attribute__((ext_vector_type(16)));

union Pack8 { __bf16 h[8]; uint4 v; };
union QPair { struct { bf16x4 lo, hi; } p; bf16x8 v; };

// one element per thread: 43008 bfrag elems + 86016 clsTT elems (incl. pad)
__global__ __launch_bounds__(256) void prep(
    const float* __restrict__ fus_w,  // (128,36,3,3)
    const float* __restrict__ cls_w,  // (10,6272)
    const float* __restrict__ reg_w,  // (6272)
    __bf16* __restrict__ bfrag,       // 43008 bf16
    float* __restrict__ clsTT)        // 86016 floats
{
    const int gid = blockIdx.x * 256 + threadIdx.x;
    if (gid < 43008) {
        const int j    = gid & 7;
        const int frag = gid >> 3;
        const int lane = frag & 63;
        const int rest = frag >> 6;         // 0..83
        const int m  = rest % 21;
        const int nt = rest / 21;
        const int n  = nt * 32 + (lane & 31);
        const int hk = lane >> 5;
        float v;
        if (m < 18) {
            const int t = m >> 1, ks = m & 1;
            const int ic = ks * 16 + hk * 8 + j;        // 0..31, all real
            v = fus_w[n * 324 + ic * 9 + t];
        } else {
            const int ps = m - 18;
            const int k  = hk * 8 + j;                  // 0..15
            const int tap = ps * 4 + (k >> 2);          // 0..11
            const int ch  = k & 3;
            v = (tap < 9) ? fus_w[n * 324 + (32 + ch) * 9 + tap] : 0.f;
        }
        bfrag[gid] = (__bf16)v;             // consecutive gid -> coalesced store
    } else if (gid < 43008 + 86016) {
        // clsTT element e, kk innermost -> fully coalesced writes
        const int e   = gid - 43008;
        const int kk  = e % 12;
        const int r0  = e / 12;
        const int l31 = r0 & 31;
        const int r1  = r0 >> 5;
        const int hk  = r1 & 1;
        const int r2  = r1 >> 1;
        const int q   = r2 & 3;
        const int r3  = r2 >> 2;
        const int mt  = r3 % 7;
        const int nt  = r3 / 7;
        const int oc   = nt * 32 + l31;
        const int cell = mt * 8 + q * 2 + hk;
        float v = 0.f;
        if (cell < 49 && kk < 11) {
            const int f = oc * 49 + cell;
            v = (kk < 10) ? cls_w[kk * 6272 + f] : reg_w[f];
        }
        clsTT[e] = v;
    }
}

// ---- per-patch producer: depthwise conv + pointwise + quantum -> actT,Q ----
// p = patch index 0..195 (>=196: no-op). xs has row stride 29.
__device__ __forceinline__ void patch_work(
    const int p, const float* __restrict__ xs, __bf16* __restrict__ actT,
    __bf16* __restrict__ Qt,
    const float* __restrict__ dw_w, const float* __restrict__ pw_w,
    const float* __restrict__ pw_b, const float* __restrict__ U)
{
    if (p >= 196) return;
    const int i = p / 14, j = p % 14;
    const int Y = 2 * i, X = 2 * j;

    float w9[9];
    #pragma unroll
    for (int t = 0; t < 9; ++t) w9[t] = dw_w[t];
    float dsum = 0.f;
    #pragma unroll
    for (int dy = 0; dy < 2; ++dy) {
        #pragma unroll
        for (int dx = 0; dx < 2; ++dx) {
            const int cy = Y + dy, cx = X + dx;
            #pragma unroll
            for (int ky = 0; ky < 3; ++ky) {
                const int yy = cy + ky - 1;
                if (yy < 0 || yy > 27) continue;
                #pragma unroll
                for (int kx = 0; kx < 3; ++kx) {
                    const int xx = cx + kx - 1;
                    if (xx < 0 || xx > 27) continue;
                    dsum += xs[yy * 29 + xx] * w9[ky * 3 + kx];
                }
            }
        }
    }
    const float dpool = 0.25f * dsum;

    // ds channels 0..31 -> row sp_o, chunks 0..3 of 5 (80B row stride)
    const int sp_o = (i + 1) * 16 + (j + 1);
    #pragma unroll
    for (int c8 = 0; c8 < 4; ++c8) {
        Pack8 pk;
        #pragma unroll
        for (int e = 0; e < 8; ++e)
            pk.h[e] = (__bf16)(pw_w[c8 * 8 + e] * dpool + pw_b[c8 * 8 + e]);
        ((uint4*)actT)[sp_o * 5 + c8] = pk.v;
    }

    // quantum patch
    const float p0 = xs[Y * 29 + X],       p1 = xs[Y * 29 + X + 1];
    const float p2 = xs[(Y + 1) * 29 + X], p3 = xs[(Y + 1) * 29 + X + 1];
    float c0, s0, c1, s1, c2, s2, c3, s3;
    sincosf(0.5f * p0, &s0, &c0);
    sincosf(0.5f * p1, &s1, &c1);
    sincosf(0.5f * p2, &s2, &c2);
    sincosf(0.5f * p3, &s3, &c3);
    float a01[4] = {c0 * c1, c0 * s1, s0 * c1, s0 * s1};
    float a23[4] = {c2 * c3, c2 * s3, s2 * c3, s2 * s3};
    float amp[16];
    #pragma unroll
    for (int hi = 0; hi < 4; ++hi)
        #pragma unroll
        for (int lo = 0; lo < 4; ++lo)
            amp[hi * 4 + lo] = a01[hi] * a23[lo];

    float meas[4] = {0.f, 0.f, 0.f, 0.f};
    #pragma unroll
    for (int m = 0; m < 16; ++m) {
        float st = 0.f;
        #pragma unroll
        for (int n = 0; n < 16; ++n) st = fmaf(U[m * 16 + n], amp[n], st);
        const float pm = st * st;
        meas[0] += ((m >> 3) & 1) ? -pm : pm;
        meas[1] += ((m >> 2) & 1) ? -pm : pm;
        meas[2] += ((m >> 1) & 1) ? -pm : pm;
        meas[3] += (m & 1) ? -pm : pm;
    }
    const int fbase = i * 56 + j * 4;
    #pragma unroll
    for (int w = 0; w < 4; ++w) {
        const int f  = fbase + w;
        const int ch = f / 196;               // 0..3 -> quantum chan
        const int sp = f - ch * 196;
        const int r2 = sp / 14 + 1, c2i = sp % 14 + 1;
        const int sp2 = r2 * 16 + c2i;
        Qt[sp2 * 4 + ch] = (__bf16)meas[w];
    }
}

// ---- consumer: 21 shift-GEMMs (dual acc) + relu/pool + classifier fold ----
__device__ __forceinline__ void conv_fold(
    const __bf16* __restrict__ actT, const __bf16* __restrict__ Qt,
    const bf16x8* __restrict__ bfr, const float4* __restrict__ cls4,
    const float fb_l, const int l31, const int hk,
    const int* __restrict__ offL, const int* __restrict__ offH,
    float* __restrict__ a11)
{
    for (int mt = 0; mt < 7; ++mt) {
        // lane's A-row: m' = mt*32 + l31 -> pooled cell + sub-pixel
        const int mp   = mt * 32 + l31;
        const int cell = mp >> 2;
        const int cc = (cell < 49) ? cell : 48;   // clamp garbage rows in-bounds
        const int py = (cc * 9363) >> 16;         // cc/7 for cc<56
        const int px = cc - py * 7;
        const int yy = 2 * py + ((mp >> 1) & 1);
        const int xx = 2 * px + (mp & 1);
        const int rowbase = yy * 16 + xx;

        // dual accumulators: ks=0 -> acc0, ks=1 -> acc1 (independent chains)
        f32x16 acc0 = {0.f,0.f,0.f,0.f,0.f,0.f,0.f,0.f,
                       0.f,0.f,0.f,0.f,0.f,0.f,0.f,0.f};
        f32x16 acc1 = {0.f,0.f,0.f,0.f,0.f,0.f,0.f,0.f,
                       0.f,0.f,0.f,0.f,0.f,0.f,0.f,0.f};

        #pragma unroll
        for (int t = 0; t < 9; ++t) {
            const int ky = t / 3, kx = t - ky * 3;
            const int row = rowbase + ky * 16 + kx;
            const __bf16* rp = actT + row * 40 + hk * 8;
            const bf16x8 af0 = *(const bf16x8*)(rp);
            const bf16x8 af1 = *(const bf16x8*)(rp + 16);
            acc0 = __builtin_amdgcn_mfma_f32_32x32x16_bf16(af0, bfr[t * 2 + 0],
                                                           acc0, 0, 0, 0);
            acc1 = __builtin_amdgcn_mfma_f32_32x32x16_bf16(af1, bfr[t * 2 + 1],
                                                           acc1, 0, 0, 0);
        }
        // packed quantum slices: K = (tap,ch); B rows for taps>8 are zero
        #pragma unroll
        for (int ps = 0; ps < 3; ++ps) {
            QPair u;
            u.p.lo = *(const bf16x4*)(Qt + (rowbase + offL[ps]) * 4);
            u.p.hi = *(const bf16x4*)(Qt + (rowbase + offH[ps]) * 4);
            if (ps & 1)
                acc1 = __builtin_amdgcn_mfma_f32_32x32x16_bf16(u.v, bfr[18 + ps],
                                                               acc1, 0, 0, 0);
            else
                acc0 = __builtin_amdgcn_mfma_f32_32x32x16_bf16(u.v, bfr[18 + ps],
                                                               acc0, 0, 0, 0);
        }

        // epilogue: relu+pool in-lane; classifier fold, 3x dwordx4 per q
        const float4* cwm = cls4 + mt * 768;      // mt stride: 4*2*32*3 float4
        #pragma unroll
        for (int q = 0; q < 4; ++q) {
            float pv = 0.f;
            #pragma unroll
            for (int s = 0; s < 4; ++s) {
                const float v = acc0[q * 4 + s] + acc1[q * 4 + s] + fb_l;
                pv += (v > 0.f ? v : 0.f);
            }
            pv *= 0.25f;
            const float4 w0 = cwm[q * 192 + 0];
            const float4 w1 = cwm[q * 192 + 1];
            const float4 w2 = cwm[q * 192 + 2];
            a11[0]  = fmaf(pv, w0.x, a11[0]);
            a11[1]  = fmaf(pv, w0.y, a11[1]);
            a11[2]  = fmaf(pv, w0.z, a11[2]);
            a11[3]  = fmaf(pv, w0.w, a11[3]);
            a11[4]  = fmaf(pv, w1.x, a11[4]);
            a11[5]  = fmaf(pv, w1.y, a11[5]);
            a11[6]  = fmaf(pv, w1.z, a11[6]);
            a11[7]  = fmaf(pv, w1.w, a11[7]);
            a11[8]  = fmaf(pv, w2.x, a11[8]);
            a11[9]  = fmaf(pv, w2.y, a11[9]);
            a11[10] = fmaf(pv, w2.z, a11[10]);
        }
    }
}

__global__ __launch_bounds__(256, 2) void quanv_fused(
    const float* __restrict__ x,      // (B,1,28,28)
    const float* __restrict__ dw_w,   // 9
    const float* __restrict__ pw_w,   // 32
    const float* __restrict__ pw_b,   // 32
    const float* __restrict__ U,      // 16x16
    const __bf16* __restrict__ bfrag, // B fragments
    const float* __restrict__ fus_b,  // 128
    const float* __restrict__ clsTT,  // lane-ordered classifier weights
    const float* __restrict__ cls_b,  // 10
    const float* __restrict__ reg_b,  // 1
    float* __restrict__ out,          // B*10 logits, then B aux
    int B)
{
    __shared__ __align__(16) __bf16 actT[2][256 * 40];  // 40,960 B, 80 B rows
    __shared__ __align__(16) __bf16 Qt[2][256 * 4];     //  4,096 B
    __shared__ float xs[2][812];                        //  6,496 B (stride 29)
    __shared__ float red[2][48];                        //    384 B

    const int b0  = blockIdx.x * 2;
    const int b1  = b0 + 1;
    const bool two = (b1 < B);
    const int tid = threadIdx.x;

    // ---- phase 0: zero actT+Qt (halo stays zero), stage images ----
    {
        uint4 z; z.x = 0; z.y = 0; z.z = 0; z.w = 0;
        uint4* a4 = (uint4*)&actT[0][0];
        for (int i = tid; i < 2560; i += 256) a4[i] = z;
        uint4* q4 = (uint4*)&Qt[0][0];
        if (tid < 256) q4[tid] = z;
        const float* xb = x + (size_t)b0 * 784;
        const int tot = two ? 1568 : 784;
        for (int i = tid; i < tot; i += 256) {
            const int img = i / 784, r = i - img * 784;
            xs[img][r + r / 28] = xb[i];    // row stride 29
        }
    }

    const int lane = tid & 63, nt = tid >> 6;
    const int l31  = lane & 31, hk = lane >> 5;
    const float fb_l = fus_b[nt * 32 + l31];
    // wave-balanced patch assignment: 49 patches per wave
    const int pidx = (lane < 49) ? nt * 49 + lane : 999;

    bf16x8 bfr[21];
    {
        const bf16x8* __restrict__ bp = ((const bf16x8*)bfrag) + (nt * 21 * 64 + lane);
        #pragma unroll
        for (int m = 0; m < 21; ++m) bfr[m] = bp[m * 64];
    }

    // per-lane-half tap offsets for the packed quantum slices
    int offL[3], offH[3];
    #pragma unroll
    for (int ps = 0; ps < 3; ++ps) {
        int tL = ps * 4 + hk * 2;
        int tH = tL + 1;
        if (tL > 8) tL = 0;       // zero-B tail: A value is a don't-care
        if (tH > 8) tH = 0;
        offL[ps] = (tL / 3) * 16 + (tL % 3);
        offH[ps] = (tH / 3) * 16 + (tH % 3);
    }

    // classifier weights, float4 view: ((...)*32 + l31)*3 float4s
    const float4* __restrict__ cls4 =
        ((const float4*)clsTT) + ((((nt * 7) * 4) * 2 + hk) * 32 + l31) * 3;

    __syncthreads();

    // ---- pipeline fill: P12(img0) ----
    patch_work(pidx, &xs[0][0], &actT[0][0], &Qt[0][0], dw_w, pw_w, pw_b, U);
    __syncthreads();

    // ---- merged steady phase: P12(img1) overlaps conv(img0), no barrier ----
    float a11_0[11];
    #pragma unroll
    for (int k = 0; k < 11; ++k) a11_0[k] = 0.f;
    if (two) patch_work(pidx, &xs[1][0], &actT[1][0], &Qt[1][0], dw_w, pw_w, pw_b, U);
    conv_fold(&actT[0][0], &Qt[0][0], bfr, cls4, fb_l, l31, hk, offL, offH, a11_0);
    __syncthreads();

    // ---- pipeline drain: conv(img1) ----
    float a11_1[11];
    #pragma unroll
    for (int k = 0; k < 11; ++k) a11_1[k] = 0.f;
    if (two) conv_fold(&actT[1][0], &Qt[1][0], bfr, cls4, fb_l, l31, hk, offL, offH, a11_1);

    // ---- reduce + output both images ----
    #pragma unroll
    for (int k = 0; k < 11; ++k) {
        float a = a11_0[k];
        float c = a11_1[k];
        #pragma unroll
        for (int off = 32; off > 0; off >>= 1) {
            a += __shfl_down(a, off, 64);
            c += __shfl_down(c, off, 64);
        }
        if (lane == 0) { red[0][k * 4 + nt] = a; red[1][k * 4 + nt] = c; }
    }
    __syncthreads();
    if (tid < 11) {
        const float v = red[0][tid * 4] + red[0][tid * 4 + 1]
                      + red[0][tid * 4 + 2] + red[0][tid * 4 + 3];
        if (tid < 10) out[b0 * 10 + tid] = v + cls_b[tid];
        else          out[B * 10 + b0]   = v + reg_b[0];
    } else if (two && tid >= 64 && tid < 75) {
        const int k = tid - 64;
        const float v = red[1][k * 4] + red[1][k * 4 + 1]
                      + red[1][k * 4 + 2] + red[1][k * 4 + 3];
        if (k < 10) out[b1 * 10 + k] = v + cls_b[k];
        else        out[B * 10 + b1] = v + reg_b[0];
    }
}

extern "C" void kernel_launch(void* const* d_in, const int* in_sizes, int n_in,
                              void* d_out, int out_size, void* d_ws, size_t ws_size,
                              hipStream_t stream) {
    const float* x    = (const float*)d_in[0];
    const float* dw_w = (const float*)d_in[1];
    const float* pw_w = (const float*)d_in[2];
    const float* pw_b = (const float*)d_in[3];
    const float* U    = (const float*)d_in[4];
    const float* fw   = (const float*)d_in[5];
    const float* fb   = (const float*)d_in[6];
    const float* cw   = (const float*)d_in[7];
    const float* cb   = (const float*)d_in[8];
    const float* rw   = (const float*)d_in[9];
    const float* rb   = (const float*)d_in[10];
    const int B = in_sizes[0] / 784;

    __bf16* bfrag = (__bf16*)d_ws;                   // 86,016 B
    float*  clsTT = (float*)((char*)d_ws + 86016);   // 344,064 B

    prep<<<(43008 + 86016 + 255) / 256, 256, 0, stream>>>(fw, cw, rw, bfrag, clsTT);
    const int nblk = (B + 1) / 2;
    quanv_fused<<<nblk, 256, 0, stream>>>(x, dw_w, pw_w, pw_b, U, bfrag, fb,
                                          clsTT, cb, rb, (float*)d_out, B);
}

// Round 9
// 108.174 us; speedup vs baseline: 1.1479x; 1.0238x over previous
//
#include <hip/hip_runtime.h>
#include <math.h>

// Fully fused quanvolution. 36->128 3x3 conv on bf16 MFMA
// (v_mfma_f32_32x32x16_bf16) as shift-GEMMs, K-packed. Two images per
// 256-thread block, software-pipelined, 2 blocks/CU (round-15 structure).
//
// Round-18 changes vs round-17:
//   * Dual accumulator REVERTED (r17: isolated test, quanv 38->41us ->
//     conv is not MFMA-chain-bound; single acc is strictly better).
//   * Fast trig in patch_work: sincosf (libm, ~40 instr w/ range
//     reduction) -> __sinf/__cosf (native v_sin/v_cos, ~4 instr).
//     Args are in [0,0.5) rad; native error ~1e-6 << bf16 quantization
//     (2^-8) that follows. Cuts ~120 VALU ops/patch from the P12 chain,
//     which is on the critical path in fill + merged phases.
//
// d_ws:
//   [0, 86016)        bfrag [nt][21 frags][lane][8 bf16]
//                       frags 0..17: t*2+ks (ic = ks*16+hk*8+j)
//                       frags 18..20: packed quantum (k=(tap,ch))
//   [86016, +344064)  clsTT fp32 [nt=4][mt=7][q=4][hk=2][l31=32][k12]

typedef __bf16 bf16x8 __attribute__((ext_vector_type(8)));
typedef __bf16 bf16x4 __attribute__((ext_vector_type(4)));
typedef float  f32x16 __attribute__((ext_vector_type(16)));

union Pack8 { __bf16 h[8]; uint4 v; };
union QPair { struct { bf16x4 lo, hi; } p; bf16x8 v; };

// one element per thread: 43008 bfrag elems + 86016 clsTT elems (incl. pad)
__global__ __launch_bounds__(256) void prep(
    const float* __restrict__ fus_w,  // (128,36,3,3)
    const float* __restrict__ cls_w,  // (10,6272)
    const float* __restrict__ reg_w,  // (6272)
    __bf16* __restrict__ bfrag,       // 43008 bf16
    float* __restrict__ clsTT)        // 86016 floats
{
    const int gid = blockIdx.x * 256 + threadIdx.x;
    if (gid < 43008) {
        const int j    = gid & 7;
        const int frag = gid >> 3;
        const int lane = frag & 63;
        const int rest = frag >> 6;         // 0..83
        const int m  = rest % 21;
        const int nt = rest / 21;
        const int n  = nt * 32 + (lane & 31);
        const int hk = lane >> 5;
        float v;
        if (m < 18) {
            const int t = m >> 1, ks = m & 1;
            const int ic = ks * 16 + hk * 8 + j;        // 0..31, all real
            v = fus_w[n * 324 + ic * 9 + t];
        } else {
            const int ps = m - 18;
            const int k  = hk * 8 + j;                  // 0..15
            const int tap = ps * 4 + (k >> 2);          // 0..11
            const int ch  = k & 3;
            v = (tap < 9) ? fus_w[n * 324 + (32 + ch) * 9 + tap] : 0.f;
        }
        bfrag[gid] = (__bf16)v;             // consecutive gid -> coalesced store
    } else if (gid < 43008 + 86016) {
        // clsTT element e, kk innermost -> fully coalesced writes
        const int e   = gid - 43008;
        const int kk  = e % 12;
        const int r0  = e / 12;
        const int l31 = r0 & 31;
        const int r1  = r0 >> 5;
        const int hk  = r1 & 1;
        const int r2  = r1 >> 1;
        const int q   = r2 & 3;
        const int r3  = r2 >> 2;
        const int mt  = r3 % 7;
        const int nt  = r3 / 7;
        const int oc   = nt * 32 + l31;
        const int cell = mt * 8 + q * 2 + hk;
        float v = 0.f;
        if (cell < 49 && kk < 11) {
            const int f = oc * 49 + cell;
            v = (kk < 10) ? cls_w[kk * 6272 + f] : reg_w[f];
        }
        clsTT[e] = v;
    }
}

// ---- per-patch producer: depthwise conv + pointwise + quantum -> actT,Q ----
// p = patch index 0..195 (>=196: no-op). xs has row stride 29.
__device__ __forceinline__ void patch_work(
    const int p, const float* __restrict__ xs, __bf16* __restrict__ actT,
    __bf16* __restrict__ Qt,
    const float* __restrict__ dw_w, const float* __restrict__ pw_w,
    const float* __restrict__ pw_b, const float* __restrict__ U)
{
    if (p >= 196) return;
    const int i = p / 14, j = p % 14;
    const int Y = 2 * i, X = 2 * j;

    float w9[9];
    #pragma unroll
    for (int t = 0; t < 9; ++t) w9[t] = dw_w[t];
    float dsum = 0.f;
    #pragma unroll
    for (int dy = 0; dy < 2; ++dy) {
        #pragma unroll
        for (int dx = 0; dx < 2; ++dx) {
            const int cy = Y + dy, cx = X + dx;
            #pragma unroll
            for (int ky = 0; ky < 3; ++ky) {
                const int yy = cy + ky - 1;
                if (yy < 0 || yy > 27) continue;
                #pragma unroll
                for (int kx = 0; kx < 3; ++kx) {
                    const int xx = cx + kx - 1;
                    if (xx < 0 || xx > 27) continue;
                    dsum += xs[yy * 29 + xx] * w9[ky * 3 + kx];
                }
            }
        }
    }
    const float dpool = 0.25f * dsum;

    // ds channels 0..31 -> row sp_o, chunks 0..3 of 5 (80B row stride)
    const int sp_o = (i + 1) * 16 + (j + 1);
    #pragma unroll
    for (int c8 = 0; c8 < 4; ++c8) {
        Pack8 pk;
        #pragma unroll
        for (int e = 0; e < 8; ++e)
            pk.h[e] = (__bf16)(pw_w[c8 * 8 + e] * dpool + pw_b[c8 * 8 + e]);
        ((uint4*)actT)[sp_o * 5 + c8] = pk.v;
    }

    // quantum patch (fast trig: args in [0,0.5) rad, error << bf16 quant)
    const float p0 = xs[Y * 29 + X],       p1 = xs[Y * 29 + X + 1];
    const float p2 = xs[(Y + 1) * 29 + X], p3 = xs[(Y + 1) * 29 + X + 1];
    const float s0 = __sinf(0.5f * p0), c0 = __cosf(0.5f * p0);
    const float s1 = __sinf(0.5f * p1), c1 = __cosf(0.5f * p1);
    const float s2 = __sinf(0.5f * p2), c2 = __cosf(0.5f * p2);
    const float s3 = __sinf(0.5f * p3), c3 = __cosf(0.5f * p3);
    float a01[4] = {c0 * c1, c0 * s1, s0 * c1, s0 * s1};
    float a23[4] = {c2 * c3, c2 * s3, s2 * c3, s2 * s3};
    float amp[16];
    #pragma unroll
    for (int hi = 0; hi < 4; ++hi)
        #pragma unroll
        for (int lo = 0; lo < 4; ++lo)
            amp[hi * 4 + lo] = a01[hi] * a23[lo];

    float meas[4] = {0.f, 0.f, 0.f, 0.f};
    #pragma unroll
    for (int m = 0; m < 16; ++m) {
        float st = 0.f;
        #pragma unroll
        for (int n = 0; n < 16; ++n) st = fmaf(U[m * 16 + n], amp[n], st);
        const float pm = st * st;
        meas[0] += ((m >> 3) & 1) ? -pm : pm;
        meas[1] += ((m >> 2) & 1) ? -pm : pm;
        meas[2] += ((m >> 1) & 1) ? -pm : pm;
        meas[3] += (m & 1) ? -pm : pm;
    }
    const int fbase = i * 56 + j * 4;
    #pragma unroll
    for (int w = 0; w < 4; ++w) {
        const int f  = fbase + w;
        const int ch = f / 196;               // 0..3 -> quantum chan
        const int sp = f - ch * 196;
        const int r2 = sp / 14 + 1, c2i = sp % 14 + 1;
        const int sp2 = r2 * 16 + c2i;
        Qt[sp2 * 4 + ch] = (__bf16)meas[w];
    }
}

// ---- consumer: 21 shift-GEMMs + in-lane relu/pool + classifier fold ----
__device__ __forceinline__ void conv_fold(
    const __bf16* __restrict__ actT, const __bf16* __restrict__ Qt,
    const bf16x8* __restrict__ bfr, const float4* __restrict__ cls4,
    const float fb_l, const int l31, const int hk,
    const int* __restrict__ offL, const int* __restrict__ offH,
    float* __restrict__ a11)
{
    for (int mt = 0; mt < 7; ++mt) {
        // lane's A-row: m' = mt*32 + l31 -> pooled cell + sub-pixel
        const int mp   = mt * 32 + l31;
        const int cell = mp >> 2;
        const int cc = (cell < 49) ? cell : 48;   // clamp garbage rows in-bounds
        const int py = (cc * 9363) >> 16;         // cc/7 for cc<56
        const int px = cc - py * 7;
        const int yy = 2 * py + ((mp >> 1) & 1);
        const int xx = 2 * px + (mp & 1);
        const int rowbase = yy * 16 + xx;

        f32x16 acc = {0.f,0.f,0.f,0.f,0.f,0.f,0.f,0.f,
                      0.f,0.f,0.f,0.f,0.f,0.f,0.f,0.f};

        #pragma unroll
        for (int t = 0; t < 9; ++t) {
            const int ky = t / 3, kx = t - ky * 3;
            const int row = rowbase + ky * 16 + kx;
            const __bf16* rp = actT + row * 40 + hk * 8;
            #pragma unroll
            for (int ks = 0; ks < 2; ++ks) {
                const bf16x8 af = *(const bf16x8*)(rp + ks * 16);
                acc = __builtin_amdgcn_mfma_f32_32x32x16_bf16(af, bfr[t * 2 + ks],
                                                              acc, 0, 0, 0);
            }
        }
        // packed quantum slices: K = (tap,ch); B rows for taps>8 are zero
        #pragma unroll
        for (int ps = 0; ps < 3; ++ps) {
            QPair u;
            u.p.lo = *(const bf16x4*)(Qt + (rowbase + offL[ps]) * 4);
            u.p.hi = *(const bf16x4*)(Qt + (rowbase + offH[ps]) * 4);
            acc = __builtin_amdgcn_mfma_f32_32x32x16_bf16(u.v, bfr[18 + ps],
                                                          acc, 0, 0, 0);
        }

        // epilogue: relu+pool in-lane; classifier fold, 3x dwordx4 per q
        const float4* cwm = cls4 + mt * 768;      // mt stride: 4*2*32*3 float4
        #pragma unroll
        for (int q = 0; q < 4; ++q) {
            float pv = 0.f;
            #pragma unroll
            for (int s = 0; s < 4; ++s) {
                const float v = acc[q * 4 + s] + fb_l;
                pv += (v > 0.f ? v : 0.f);
            }
            pv *= 0.25f;
            const float4 w0 = cwm[q * 192 + 0];
            const float4 w1 = cwm[q * 192 + 1];
            const float4 w2 = cwm[q * 192 + 2];
            a11[0]  = fmaf(pv, w0.x, a11[0]);
            a11[1]  = fmaf(pv, w0.y, a11[1]);
            a11[2]  = fmaf(pv, w0.z, a11[2]);
            a11[3]  = fmaf(pv, w0.w, a11[3]);
            a11[4]  = fmaf(pv, w1.x, a11[4]);
            a11[5]  = fmaf(pv, w1.y, a11[5]);
            a11[6]  = fmaf(pv, w1.z, a11[6]);
            a11[7]  = fmaf(pv, w1.w, a11[7]);
            a11[8]  = fmaf(pv, w2.x, a11[8]);
            a11[9]  = fmaf(pv, w2.y, a11[9]);
            a11[10] = fmaf(pv, w2.z, a11[10]);
        }
    }
}

__global__ __launch_bounds__(256, 2) void quanv_fused(
    const float* __restrict__ x,      // (B,1,28,28)
    const float* __restrict__ dw_w,   // 9
    const float* __restrict__ pw_w,   // 32
    const float* __restrict__ pw_b,   // 32
    const float* __restrict__ U,      // 16x16
    const __bf16* __restrict__ bfrag, // B fragments
    const float* __restrict__ fus_b,  // 128
    const float* __restrict__ clsTT,  // lane-ordered classifier weights
    const float* __restrict__ cls_b,  // 10
    const float* __restrict__ reg_b,  // 1
    float* __restrict__ out,          // B*10 logits, then B aux
    int B)
{
    __shared__ __align__(16) __bf16 actT[2][256 * 40];  // 40,960 B, 80 B rows
    __shared__ __align__(16) __bf16 Qt[2][256 * 4];     //  4,096 B
    __shared__ float xs[2][812];                        //  6,496 B (stride 29)
    __shared__ float red[2][48];                        //    384 B

    const int b0  = blockIdx.x * 2;
    const int b1  = b0 + 1;
    const bool two = (b1 < B);
    const int tid = threadIdx.x;

    // ---- phase 0: zero actT+Qt (halo stays zero), stage images ----
    {
        uint4 z; z.x = 0; z.y = 0; z.z = 0; z.w = 0;
        uint4* a4 = (uint4*)&actT[0][0];
        for (int i = tid; i < 2560; i += 256) a4[i] = z;
        uint4* q4 = (uint4*)&Qt[0][0];
        if (tid < 256) q4[tid] = z;
        const float* xb = x + (size_t)b0 * 784;
        const int tot = two ? 1568 : 784;
        for (int i = tid; i < tot; i += 256) {
            const int img = i / 784, r = i - img * 784;
            xs[img][r + r / 28] = xb[i];    // row stride 29
        }
    }

    const int lane = tid & 63, nt = tid >> 6;
    const int l31  = lane & 31, hk = lane >> 5;
    const float fb_l = fus_b[nt * 32 + l31];
    // wave-balanced patch assignment: 49 patches per wave
    const int pidx = (lane < 49) ? nt * 49 + lane : 999;

    bf16x8 bfr[21];
    {
        const bf16x8* __restrict__ bp = ((const bf16x8*)bfrag) + (nt * 21 * 64 + lane);
        #pragma unroll
        for (int m = 0; m < 21; ++m) bfr[m] = bp[m * 64];
    }

    // per-lane-half tap offsets for the packed quantum slices
    int offL[3], offH[3];
    #pragma unroll
    for (int ps = 0; ps < 3; ++ps) {
        int tL = ps * 4 + hk * 2;
        int tH = tL + 1;
        if (tL > 8) tL = 0;       // zero-B tail: A value is a don't-care
        if (tH > 8) tH = 0;
        offL[ps] = (tL / 3) * 16 + (tL % 3);
        offH[ps] = (tH / 3) * 16 + (tH % 3);
    }

    // classifier weights, float4 view: ((...)*32 + l31)*3 float4s
    const float4* __restrict__ cls4 =
        ((const float4*)clsTT) + ((((nt * 7) * 4) * 2 + hk) * 32 + l31) * 3;

    __syncthreads();

    // ---- pipeline fill: P12(img0) ----
    patch_work(pidx, &xs[0][0], &actT[0][0], &Qt[0][0], dw_w, pw_w, pw_b, U);
    __syncthreads();

    // ---- merged steady phase: P12(img1) overlaps conv(img0), no barrier ----
    float a11_0[11];
    #pragma unroll
    for (int k = 0; k < 11; ++k) a11_0[k] = 0.f;
    if (two) patch_work(pidx, &xs[1][0], &actT[1][0], &Qt[1][0], dw_w, pw_w, pw_b, U);
    conv_fold(&actT[0][0], &Qt[0][0], bfr, cls4, fb_l, l31, hk, offL, offH, a11_0);
    __syncthreads();

    // ---- pipeline drain: conv(img1) ----
    float a11_1[11];
    #pragma unroll
    for (int k = 0; k < 11; ++k) a11_1[k] = 0.f;
    if (two) conv_fold(&actT[1][0], &Qt[1][0], bfr, cls4, fb_l, l31, hk, offL, offH, a11_1);

    // ---- reduce + output both images ----
    #pragma unroll
    for (int k = 0; k < 11; ++k) {
        float a = a11_0[k];
        float c = a11_1[k];
        #pragma unroll
        for (int off = 32; off > 0; off >>= 1) {
            a += __shfl_down(a, off, 64);
            c += __shfl_down(c, off, 64);
        }
        if (lane == 0) { red[0][k * 4 + nt] = a; red[1][k * 4 + nt] = c; }
    }
    __syncthreads();
    if (tid < 11) {
        const float v = red[0][tid * 4] + red[0][tid * 4 + 1]
                      + red[0][tid * 4 + 2] + red[0][tid * 4 + 3];
        if (tid < 10) out[b0 * 10 + tid] = v + cls_b[tid];
        else          out[B * 10 + b0]   = v + reg_b[0];
    } else if (two && tid >= 64 && tid < 75) {
        const int k = tid - 64;
        const float v = red[1][k * 4] + red[1][k * 4 + 1]
                      + red[1][k * 4 + 2] + red[1][k * 4 + 3];
        if (k < 10) out[b1 * 10 + k] = v + cls_b[k];
        else        out[B * 10 + b1] = v + reg_b[0];
    }
}

extern "C" void kernel_launch(void* const* d_in, const int* in_sizes, int n_in,
                              void* d_out, int out_size, void* d_ws, size_t ws_size,
                              hipStream_t stream) {
    const float* x    = (const float*)d_in[0];
    const float* dw_w = (const float*)d_in[1];
    const float* pw_w = (const float*)d_in[2];
    const float* pw_b = (const float*)d_in[3];
    const float* U    = (const float*)d_in[4];
    const float* fw   = (const float*)d_in[5];
    const float* fb   = (const float*)d_in[6];
    const float* cw   = (const float*)d_in[7];
    const float* cb   = (const float*)d_in[8];
    const float* rw   = (const float*)d_in[9];
    const float* rb   = (const float*)d_in[10];
    const int B = in_sizes[0] / 784;

    __bf16* bfrag = (__bf16*)d_ws;                   // 86,016 B
    float*  clsTT = (float*)((char*)d_ws + 86016);   // 344,064 B

    prep<<<(43008 + 86016 + 255) / 256, 256, 0, stream>>>(fw, cw, rw, bfrag, clsTT);
    const int nblk = (B + 1) / 2;
    quanv_fused<<<nblk, 256, 0, stream>>>(x, dw_w, pw_w, pw_b, U, bfrag, fb,
                                          clsTT, cb, rb, (float*)d_out, B);
}